// Round 5
// baseline (15.534 us; speedup 1.0000x reference)
//
#include <hip/hip_runtime.h>
#include <math.h>

// ---- problem constants ----
// SIZE=(60,270,480); CHANNELS=14; GRIDS: (60,16,16,8),(30,8,8,4),(15,4,4,2)
// IDX_MAX=(60,3,5) -> patch=(1,90,96); PADDING=(0,1,1) -> ppad=(1,92,98)
// t_embed: [64][1][92][98][14] = 8,078,336 f32 ; t_manip: [64][16]

#define N_PATCH 64
#define PPAD_H 92
#define PPAD_W 98
#define CH 14
#define PIX_PER_PATCH (PPAD_H * PPAD_W)            // 9016
#define F2_PER_PATCH (PIX_PER_PATCH * CH / 2)      // 63112 float2 per patch
#define BLOCKS_PER_PATCH 28
#define SLICE (F2_PER_PATCH / BLOCKS_PER_PATCH)    // 2254 exact (63112 = 28*2254)
#define TOTAL_EMBED (N_PATCH * PIX_PER_PATCH * CH)
#define TOTAL_MANIP (N_PATCH * 16)

// combined grid layout in LDS: L0 t-plane [0,2048), L1 t-lerped [2048,2304), L2 [2304,2336)
#define L1_BASE 2048
#define L2_BASE 2304

__device__ __forceinline__ float lerpf(float a, float b, float f) {
    return a + f * (b - a);
}

__global__ __launch_bounds__(256) void embed_kernel(
    const int* __restrict__ idx,
    const float* __restrict__ g0,
    const float* __restrict__ g1,
    const float* __restrict__ g2,
    float* __restrict__ out)
{
    __shared__ float  s_grid[2336];           // 9.1 KB: all three levels, t-collapsed
    __shared__ float4 s_hl[3][PPAD_H];        // (off0_bits, off1_bits, frac, mask)
    __shared__ float4 s_wl[3][PPAD_W];

    const int tid = threadIdx.x;
    const int n   = blockIdx.y;
    const int it  = idx[3 * n + 0];
    const int ih  = idx[3 * n + 1];
    const int iw  = idx[3 * n + 2];

    // ---- stage level-0 t-plane (identity in T): 2048 floats = 512 float4 ----
    {
        const float4* src = (const float4*)(g0 + (size_t)it * 2048);
        float4* dst = (float4*)s_grid;
        for (int i = tid; i < 512; i += 256) dst[i] = src[i];
    }
    // ---- stage level-1 with t-lerp pre-applied: 256 floats ----
    {
        float xt = ((float)it + 0.5f) * 0.5f - 0.5f;   // 30/60 = 0.5 exact
        float ftf = floorf(xt);
        float ft  = xt - ftf;
        int t0 = (int)ftf;
        int t0c = min(max(t0, 0), 29), t1c = min(t0 + 1, 29);
        const float* p0 = g1 + t0c * 256;
        const float* p1 = g1 + t1c * 256;
        if (tid < 256) s_grid[L1_BASE + tid] = lerpf(p0[tid], p1[tid], ft);
    }
    // ---- stage level-2 with t-lerp pre-applied: 32 floats ----
    {
        float xt = ((float)it + 0.5f) * 0.25f - 0.5f;  // 15/60 = 0.25 exact
        float ftf = floorf(xt);
        float ft  = xt - ftf;
        int t0 = (int)ftf;
        int t0c = min(max(t0, 0), 14), t1c = min(t0 + 1, 14);
        const float* p0 = g2 + t0c * 32;
        const float* p1 = g2 + t1c * 32;
        if (tid < 32) s_grid[L2_BASE + tid] = lerpf(p0[tid], p1[tid], ft);
    }
    // ---- h LUTs: clamped row offsets (element units) + frac + mask ----
    if (tid < PPAD_H) {
        int rh = ih * 90 + tid - 1;
        float ok = ((unsigned)rh < 270u) ? 1.0f : 0.0f;
        const int   Hgs[3] = {16, 8, 4};
        const int   rst[3] = {16 * 8, 8 * 4, 4 * 2};
        const float shs[3] = {(float)((double)16 / 270.0),
                              (float)((double)8  / 270.0),
                              (float)((double)4  / 270.0)};
        #pragma unroll
        for (int l = 0; l < 3; ++l) {
            float xh = ((float)rh + 0.5f) * shs[l] - 0.5f;
            float ff = floorf(xh);
            float f  = xh - ff;
            int h0 = (int)ff;
            int h0c = min(max(h0, 0), Hgs[l] - 1);
            int h1c = min(h0 + 1, Hgs[l] - 1);
            s_hl[l][tid] = make_float4(__int_as_float(h0c * rst[l]),
                                       __int_as_float(h1c * rst[l]), f, ok);
        }
    }
    // ---- w LUTs: clamped col offsets (element units) + frac + mask ----
    if (tid < PPAD_W) {
        int rw = iw * 96 + tid - 1;
        float ok = ((unsigned)rw < 480u) ? 1.0f : 0.0f;
        const int   Wgs[3] = {16, 8, 4};
        const int   cst[3] = {8, 4, 2};
        const float sws[3] = {(float)((double)16 / 480.0),
                              (float)((double)8  / 480.0),
                              (float)((double)4  / 480.0)};
        #pragma unroll
        for (int l = 0; l < 3; ++l) {
            float xw = ((float)rw + 0.5f) * sws[l] - 0.5f;
            float ff = floorf(xw);
            float f  = xw - ff;
            int w0 = (int)ff;
            int w0c = min(max(w0, 0), Wgs[l] - 1);
            int w1c = min(w0 + 1, Wgs[l] - 1);
            s_wl[l][tid] = make_float4(__int_as_float(w0c * cst[l]),
                                       __int_as_float(w1c * cst[l]), f, ok);
        }
    }

    // ---- fused manip (one block only): 1024 outputs, f64 sin/cos of f32 arg ----
    if (blockIdx.x == 0 && n == 0) {
        float* om = out + TOTAL_EMBED;
        for (int e = tid; e < TOTAL_MANIP; e += 256) {
            int nn = e >> 4;
            int j  = e & 15;
            int l  = j & 7;
            float base = (float)M_PI * (float)(1 << l);  // fl32(2^l*pi), pow2 exact
            float v = (float)idx[3 * nn + 0] * base;     // f32 mul = reference
            double dv = (double)v;
            om[e] = (float)((j < 8) ? sin(dv) : cos(dv));
        }
    }

    __syncthreads();   // staging complete before ANY compute reads LDS

    // ---- stream: one thread per output float2, fully coalesced stores ----
    // float2 index lj within patch: pixel p = lj/7, pair q = lj%7.
    // q in 0..3 -> level0 channels (2q,2q+1); q=4,5 -> level1; q=6 -> level2.
    const int lj0 = blockIdx.x * SLICE;
    const int ljend = lj0 + SLICE;
    float2* o = ((float2*)out) + (size_t)n * F2_PER_PATCH;

    for (int lj = lj0 + tid; lj < ljend; lj += 256) {
        unsigned p = (unsigned)lj / 7u;
        int q = lj - 7 * (int)p;
        unsigned hh = p / 98u;
        int ww = (int)p - 98 * (int)hh;

        int lvl = (q >= 4) + (q >= 6);
        // channel-pair base within combined grid array
        int cb = 2 * q;                          // level 0: pairs at 0,2,4,6
        if (lvl == 1) cb = L1_BASE - 8 + 2 * q;  // q=4 -> 2048, q=5 -> 2050
        if (lvl == 2) cb = L2_BASE;              // q=6 -> 2304

        float4 hl = s_hl[lvl][hh];
        float4 wl = s_wl[lvl][ww];
        int ho0 = __float_as_int(hl.x), ho1 = __float_as_int(hl.y);
        int wo0 = __float_as_int(wl.x), wo1 = __float_as_int(wl.y);
        float fh = hl.z, fw = wl.z;
        float mm = hl.w * wl.w;                  // border mask (t always in range)

        const float* gb = s_grid + cb;
        float2 a = *(const float2*)(gb + ho0 + wo0);
        float2 b = *(const float2*)(gb + ho0 + wo1);
        float2 c = *(const float2*)(gb + ho1 + wo0);
        float2 d = *(const float2*)(gb + ho1 + wo1);

        float2 r;
        r.x = mm * lerpf(lerpf(a.x, b.x, fw), lerpf(c.x, d.x, fw), fh);
        r.y = mm * lerpf(lerpf(a.y, b.y, fw), lerpf(c.y, d.y, fw), fh);
        o[lj] = r;
    }
}

extern "C" void kernel_launch(void* const* d_in, const int* in_sizes, int n_in,
                              void* d_out, int out_size, void* d_ws, size_t ws_size,
                              hipStream_t stream) {
    const int*   idx = (const int*)  d_in[0];
    const float* g0  = (const float*)d_in[3];
    const float* g1  = (const float*)d_in[4];
    const float* g2  = (const float*)d_in[5];
    float* out = (float*)d_out;

    dim3 grid(BLOCKS_PER_PATCH, N_PATCH);   // (28, 64) = 1792 blocks = 7/CU
    embed_kernel<<<grid, 256, 0, stream>>>(idx, g0, g1, g2, out);
}

// Round 6
// 12.759 us; speedup vs baseline: 1.2175x; 1.2175x over previous
//
#include <hip/hip_runtime.h>
#include <math.h>

// ---- problem constants ----
// SIZE=(60,270,480); CHANNELS=14; GRIDS: (60,16,16,8),(30,8,8,4),(15,4,4,2)
// IDX_MAX=(60,3,5) -> patch=(1,90,96); PADDING=(0,1,1) -> ppad=(1,92,98)
// t_embed: [64][1][92][98][14] = 8,078,336 f32 ; t_manip: [64][16]

#define N_PATCH 64
#define PPAD_H 92
#define PPAD_W 98
#define CH 14
#define PIX_PER_PATCH (PPAD_H * PPAD_W)        // 9016
#define ROWS_PER_BLOCK 2
#define BLOCKS_PER_PATCH 46                    // 46*2 = 92 rows
#define PX_PER_BLOCK 196                       // 2 rows * 98
#define F4_PER_BLOCK (PX_PER_BLOCK * CH / 4)   // 686
#define ELEMS_PER_PATCH (PIX_PER_PATCH * CH)   // 126224
#define ELEMS_PER_BLOCK (PX_PER_BLOCK * CH)    // 2744
#define TOTAL_EMBED (N_PATCH * ELEMS_PER_PATCH)
#define TOTAL_MANIP (N_PATCH * 16)

// per-row V-record layout (elements): L0 [0,48)=6cells*8ch, L1 [48,64)=4*4, L2 [64,70)=3*2
#define RB_STRIDE 72   // padded to keep rows 16B-aligned
#define L1_OFF 48
#define L2_OFF 64

__device__ __forceinline__ float lerpf(float a, float b, float f) {
    return a + f * (b - a);
}

// first (leftmost) clamped w-cell for this patch at a given level
__device__ __forceinline__ int wcell0(int rw0, float sw, int Wg) {
    float x = ((float)rw0 + 0.5f) * sw - 0.5f;
    int w0 = (int)floorf(x);
    return min(max(w0, 0), Wg - 1);
}

__global__ __launch_bounds__(256) void embed_kernel(
    const int* __restrict__ idx,
    const float* __restrict__ g0,
    const float* __restrict__ g1,
    const float* __restrict__ g2,
    float* __restrict__ out)
{
    __shared__ __align__(16) float s_V[ROWS_PER_BLOCK * RB_STRIDE];  // 576 B
    __shared__ float4 s_wl[3][PPAD_W];                               // 4.7 KB
    __shared__ __align__(16) float s_buf[PX_PER_BLOCK * CH];         // 11 KB

    const int tid = threadIdx.x;
    const int bx  = blockIdx.x;
    const int n   = blockIdx.y;
    const int it  = idx[3 * n + 0];
    const int ih  = idx[3 * n + 1];
    const int iw  = idx[3 * n + 2];
    const int rw0 = iw * 96 - 1;

    const float sw0 = (float)((double)16 / 480.0);
    const float sw1 = (float)((double)8  / 480.0);
    const float sw2 = (float)((double)4  / 480.0);
    const float sh0 = (float)((double)16 / 270.0);
    const float sh1 = (float)((double)8  / 270.0);
    const float sh2 = (float)((double)4  / 270.0);

    // ---- fused manip (one block only) ----
    if (bx == 0 && n == 0) {
        float* om = out + TOTAL_EMBED;
        for (int e = tid; e < TOTAL_MANIP; e += 256) {
            int nn = e >> 4;
            int j  = e & 15;
            int l  = j & 7;
            float base = (float)M_PI * (float)(1 << l);  // fl32(2^l*pi), pow2 exact
            float v = (float)idx[3 * nn + 0] * base;     // f32 mul = reference
            double dv = (double)v;
            om[e] = (float)((j < 8) ? sin(dv) : cos(dv));
        }
    }

    // ---- build per-row V tables (h,t-lerped, row-mask folded) ----
    if (tid < 96) {
        // L0: 2 rows x 6 cells x 8 ch; T is identity (t = it exactly)
        int chn  = tid & 7;
        int u    = tid >> 3;          // 0..11
        int row  = (u >= 6);
        int cell = u - 6 * row;
        int rh   = ih * 90 + (bx * 2 + row) - 1;
        float mh = ((unsigned)rh < 270u) ? 1.0f : 0.0f;
        float xh = ((float)rh + 0.5f) * sh0 - 0.5f;
        float ff = floorf(xh);
        float fh = xh - ff;
        int h0 = (int)ff;
        int h0c = min(max(h0, 0), 15), h1c = min(h0 + 1, 15);
        int cw = min(wcell0(rw0, sw0, 16) + cell, 15);
        const float* base = g0 + (size_t)it * 2048;
        float a = base[(h0c * 16 + cw) * 8 + chn];
        float b = base[(h1c * 16 + cw) * 8 + chn];
        s_V[row * RB_STRIDE + cell * 8 + chn] = mh * lerpf(a, b, fh);
    } else if (tid < 128) {
        // L1: 2 rows x 4 cells x 4 ch; t-lerp + h-lerp
        int i    = tid - 96;          // 0..31
        int chn  = i & 3;
        int u    = i >> 2;            // 0..7
        int row  = (u >= 4);
        int cell = u - 4 * row;
        int rh   = ih * 90 + (bx * 2 + row) - 1;
        float mh = ((unsigned)rh < 270u) ? 1.0f : 0.0f;
        float xh = ((float)rh + 0.5f) * sh1 - 0.5f;
        float ff = floorf(xh);
        float fh = xh - ff;
        int h0 = (int)ff;
        int h0c = min(max(h0, 0), 7), h1c = min(h0 + 1, 7);
        float xt = ((float)it + 0.5f) * 0.5f - 0.5f;     // 30/60 exact
        float ftf = floorf(xt);
        float ft  = xt - ftf;
        int t0 = (int)ftf;
        int t0c = min(max(t0, 0), 29), t1c = min(t0 + 1, 29);
        int cw = min(wcell0(rw0, sw1, 8) + cell, 7);
        float a00 = g1[((t0c * 8 + h0c) * 8 + cw) * 4 + chn];
        float a01 = g1[((t0c * 8 + h1c) * 8 + cw) * 4 + chn];
        float a10 = g1[((t1c * 8 + h0c) * 8 + cw) * 4 + chn];
        float a11 = g1[((t1c * 8 + h1c) * 8 + cw) * 4 + chn];
        s_V[row * RB_STRIDE + L1_OFF + cell * 4 + chn] =
            mh * lerpf(lerpf(a00, a01, fh), lerpf(a10, a11, fh), ft);
    } else if (tid < 140) {
        // L2: 2 rows x 3 cells x 2 ch
        int i    = tid - 128;         // 0..11
        int chn  = i & 1;
        int u    = i >> 1;            // 0..5
        int row  = (u >= 3);
        int cell = u - 3 * row;
        int rh   = ih * 90 + (bx * 2 + row) - 1;
        float mh = ((unsigned)rh < 270u) ? 1.0f : 0.0f;
        float xh = ((float)rh + 0.5f) * sh2 - 0.5f;
        float ff = floorf(xh);
        float fh = xh - ff;
        int h0 = (int)ff;
        int h0c = min(max(h0, 0), 3), h1c = min(h0 + 1, 3);
        float xt = ((float)it + 0.5f) * 0.25f - 0.5f;    // 15/60 exact
        float ftf = floorf(xt);
        float ft  = xt - ftf;
        int t0 = (int)ftf;
        int t0c = min(max(t0, 0), 14), t1c = min(t0 + 1, 14);
        int cw = min(wcell0(rw0, sw2, 4) + cell, 3);
        float a00 = g2[((t0c * 4 + h0c) * 4 + cw) * 2 + chn];
        float a01 = g2[((t0c * 4 + h1c) * 4 + cw) * 2 + chn];
        float a10 = g2[((t1c * 4 + h0c) * 4 + cw) * 2 + chn];
        float a11 = g2[((t1c * 4 + h1c) * 4 + cw) * 2 + chn];
        s_V[row * RB_STRIDE + L2_OFF + cell * 2 + chn] =
            mh * lerpf(lerpf(a00, a01, fh), lerpf(a10, a11, fh), ft);
    }

    // ---- per-w LUT: (offA, offB, fw, mask) per level, offsets into V record ----
    for (int i = tid; i < 3 * PPAD_W; i += 256) {
        int lvl = (i >= PPAD_W) + (i >= 2 * PPAD_W);
        int ww  = i - PPAD_W * lvl;
        int Wg  = (lvl == 0) ? 16 : ((lvl == 1) ? 8 : 4);
        int cs  = (lvl == 0) ? 8  : ((lvl == 1) ? 4 : 2);
        int bb  = (lvl == 0) ? 0  : ((lvl == 1) ? L1_OFF : L2_OFF);
        float sw = (lvl == 0) ? sw0 : ((lvl == 1) ? sw1 : sw2);
        int rw = iw * 96 + ww - 1;
        float mask = ((unsigned)rw < 480u) ? 1.0f : 0.0f;
        float x  = ((float)rw + 0.5f) * sw - 0.5f;
        float ff = floorf(x);
        float f  = x - ff;
        int w0 = (int)ff;
        int wa = min(max(w0, 0), Wg - 1);
        int wb = min(w0 + 1, Wg - 1);
        int C0 = wcell0(rw0, sw, Wg);
        s_wl[lvl][ww] = make_float4(__int_as_float(bb + (wa - C0) * cs),
                                    __int_as_float(bb + (wb - C0) * cs), f, mask);
    }

    __syncthreads();

    // ---- per-pixel: 14 channels = 1 w-lerp each from V tables ----
    if (tid < PX_PER_BLOCK) {
        int row = (tid >= PPAD_W);
        int ww  = tid - PPAD_W * row;
        const float* V = s_V + row * RB_STRIDE;
        float r[CH];

        float4 wl0 = s_wl[0][ww];
        {
            int oA = __float_as_int(wl0.x), oB = __float_as_int(wl0.y);
            float fw = wl0.z;
            float4 A0 = *(const float4*)(V + oA);
            float4 A1 = *(const float4*)(V + oA + 4);
            float4 B0 = *(const float4*)(V + oB);
            float4 B1 = *(const float4*)(V + oB + 4);
            r[0] = lerpf(A0.x, B0.x, fw);
            r[1] = lerpf(A0.y, B0.y, fw);
            r[2] = lerpf(A0.z, B0.z, fw);
            r[3] = lerpf(A0.w, B0.w, fw);
            r[4] = lerpf(A1.x, B1.x, fw);
            r[5] = lerpf(A1.y, B1.y, fw);
            r[6] = lerpf(A1.z, B1.z, fw);
            r[7] = lerpf(A1.w, B1.w, fw);
        }
        {
            float4 wl1 = s_wl[1][ww];
            int oA = __float_as_int(wl1.x), oB = __float_as_int(wl1.y);
            float fw = wl1.z;
            float4 A = *(const float4*)(V + oA);
            float4 B = *(const float4*)(V + oB);
            r[8]  = lerpf(A.x, B.x, fw);
            r[9]  = lerpf(A.y, B.y, fw);
            r[10] = lerpf(A.z, B.z, fw);
            r[11] = lerpf(A.w, B.w, fw);
        }
        {
            float4 wl2 = s_wl[2][ww];
            int oA = __float_as_int(wl2.x), oB = __float_as_int(wl2.y);
            float fw = wl2.z;
            float2 A = *(const float2*)(V + oA);
            float2 B = *(const float2*)(V + oB);
            r[12] = lerpf(A.x, B.x, fw);
            r[13] = lerpf(A.y, B.y, fw);
        }
        float mw = wl0.w;   // w-mask (same for all levels; h-mask folded into V)
        float2* b = (float2*)(s_buf + tid * CH);
        b[0] = make_float2(mw * r[0],  mw * r[1]);
        b[1] = make_float2(mw * r[2],  mw * r[3]);
        b[2] = make_float2(mw * r[4],  mw * r[5]);
        b[3] = make_float2(mw * r[6],  mw * r[7]);
        b[4] = make_float2(mw * r[8],  mw * r[9]);
        b[5] = make_float2(mw * r[10], mw * r[11]);
        b[6] = make_float2(mw * r[12], mw * r[13]);
    }
    __syncthreads();

    // ---- coalesced store: 686 float4 = 2744 floats (16B-aligned base) ----
    const float4* sb = (const float4*)s_buf;
    float4* gb = (float4*)(out + (size_t)n * ELEMS_PER_PATCH + bx * ELEMS_PER_BLOCK);
    for (int j = tid; j < F4_PER_BLOCK; j += 256) gb[j] = sb[j];
}

extern "C" void kernel_launch(void* const* d_in, const int* in_sizes, int n_in,
                              void* d_out, int out_size, void* d_ws, size_t ws_size,
                              hipStream_t stream) {
    const int*   idx = (const int*)  d_in[0];
    const float* g0  = (const float*)d_in[3];
    const float* g1  = (const float*)d_in[4];
    const float* g2  = (const float*)d_in[5];
    float* out = (float*)d_out;

    dim3 grid(BLOCKS_PER_PATCH, N_PATCH);   // (46, 64) = 2944 blocks
    embed_kernel<<<grid, 256, 0, stream>>>(idx, g0, g1, g2, out);
}